// Round 2
// baseline (1334.862 us; speedup 1.0000x reference)
//
#include <hip/hip_runtime.h>
#include <stdint.h>

// JTMPN on MI355X — round 2: fuse gather-sum into the MFMA GEMM.
// Block = 64 rows x 512 cols, 8 waves; per K-chunk(64) gather 128B/row/idx
// (one cacheline) into LDS, then 2 MFMA K-steps. 2 blocks/CU so gather
// (memory) and MFMA phases of co-resident blocks overlap.

#define MAX_NB 15
#define HID 512
#define NA 32768
#define NB 65536
#define NMESS 8192

typedef unsigned short u16;
typedef unsigned int u32;
typedef __bf16 bf16x8 __attribute__((ext_vector_type(8)));
typedef float f32x4 __attribute__((ext_vector_type(4)));

__device__ __forceinline__ u16 f2bf(float f) {
  u32 u = __builtin_bit_cast(u32, f);
  u32 r = (u + 0x7fffu + ((u >> 16) & 1u)) >> 16;
  return (u16)r;
}
__device__ __forceinline__ float bf2f(u16 b) {
  u32 u = ((u32)b) << 16;
  return __builtin_bit_cast(float, u);
}
__device__ __forceinline__ float bflo(u32 u) {
  return __builtin_bit_cast(float, u << 16);
}
__device__ __forceinline__ float bfhi(u32 u) {
  return __builtin_bit_cast(float, u & 0xffff0000u);
}

__device__ __forceinline__ void async16(const u16* g, u16* l) {
  __builtin_amdgcn_global_load_lds(
      (const __attribute__((address_space(1))) u32*)g,
      (__attribute__((address_space(3))) u32*)l, 16, 0, 0);
}

// ---------------- prep: fp32 -> bf16 conversions / transposes ----------------
// tree_bf [8192][512], fbpad [65536][64], Wi^T [512][64], Wh^T [512][512],
// Wo^T remapped+padded [512][576]
__global__ __launch_bounds__(256) void prep_kernel(
    const float* __restrict__ fbonds, const float* __restrict__ tree,
    const float* __restrict__ Wi, const float* __restrict__ Wh,
    const float* __restrict__ Wo, u16* __restrict__ tree_bf,
    u16* __restrict__ fbpad, u16* __restrict__ wi_t, u16* __restrict__ wh_t,
    u16* __restrict__ wo_t) {
  int t = blockIdx.x * 256 + threadIdx.x;
  const int N0 = NMESS * HID;  // 4194304
  const int N1 = NB * 64;      // 4194304
  const int N2 = 512 * 64;
  const int N3 = 512 * 512;
  const int N4 = 512 * 576;
  if (t < N0) { tree_bf[t] = f2bf(tree[t]); return; }
  t -= N0;
  if (t < N1) {
    int row = t >> 6, c = t & 63;
    fbpad[t] = (c < 40) ? f2bf(fbonds[row * 40 + c]) : (u16)0;
    return;
  }
  t -= N1;
  if (t < N2) {
    int n = t >> 6, k = t & 63;
    wi_t[t] = (k < 40) ? f2bf(Wi[k * 512 + n]) : (u16)0;
    return;
  }
  t -= N2;
  if (t < N3) {
    int n = t >> 9, k = t & 511;
    wh_t[t] = f2bf(Wh[k * 512 + n]);
    return;
  }
  t -= N3;
  if (t < N4) {
    int n = t / 576, k = t - n * 576;
    float v = 0.f;
    if (k < 512) v = Wo[(35 + k) * 512 + n];        // nei part
    else if (k < 547) v = Wo[(k - 512) * 512 + n];  // fatoms part
    wo_t[t] = f2bf(v);
    return;
  }
}

// ---------------- init GEMM: binput = fbpad @ Wi, gm0 = relu(binput) --------
// 128x128 tile, K=64, grid (NB/128, 4)
__global__ __launch_bounds__(256) void init_gemm(
    const u16* __restrict__ A, const u16* __restrict__ Bt,
    u16* __restrict__ binput, u16* __restrict__ gm0) {
  const int K = 64;
  __shared__ __align__(16) u16 As[128 * 32];
  __shared__ __align__(16) u16 Bs[128 * 32];
  const int t = threadIdx.x;
  const int lane = t & 63;
  const int w = t >> 6;
  const int wm = w & 1, wn = w >> 1;
  const int mBase = blockIdx.x * 128;
  const int nBase = blockIdx.y * 128;
  const int r = t >> 2;
  const int c8 = (t & 3) * 8;
  const int q8 = (lane >> 4) * 8;
  const int l15 = lane & 15;

  f32x4 acc[4][4];
#pragma unroll
  for (int i = 0; i < 4; i++)
#pragma unroll
    for (int j = 0; j < 4; j++)
#pragma unroll
      for (int rg = 0; rg < 4; rg++) acc[i][j][rg] = 0.f;

  for (int kb = 0; kb < K; kb += 32) {
    __syncthreads();
    async16(A + (size_t)(mBase + r) * K + kb + c8, As + r * 32 + c8);
    async16(A + (size_t)(mBase + r + 64) * K + kb + c8, As + (r + 64) * 32 + c8);
    async16(Bt + (size_t)(nBase + r) * K + kb + c8, Bs + r * 32 + c8);
    async16(Bt + (size_t)(nBase + r + 64) * K + kb + c8, Bs + (r + 64) * 32 + c8);
    __syncthreads();
    bf16x8 av[4], bv[4];
#pragma unroll
    for (int i = 0; i < 4; i++)
      av[i] = *(const bf16x8*)(As + (wm * 64 + i * 16 + l15) * 32 + q8);
#pragma unroll
    for (int j = 0; j < 4; j++)
      bv[j] = *(const bf16x8*)(Bs + (wn * 64 + j * 16 + l15) * 32 + q8);
#pragma unroll
    for (int i = 0; i < 4; i++)
#pragma unroll
      for (int j = 0; j < 4; j++)
        acc[i][j] = __builtin_amdgcn_mfma_f32_16x16x32_bf16(av[i], bv[j],
                                                            acc[i][j], 0, 0, 0);
  }
#pragma unroll
  for (int i = 0; i < 4; i++) {
    int row = mBase + wm * 64 + i * 16 + (lane >> 4) * 4;
#pragma unroll
    for (int j = 0; j < 4; j++) {
      int col = nBase + wn * 64 + j * 16 + l15;
#pragma unroll
      for (int rg = 0; rg < 4; rg++) {
        float v = acc[i][j][rg];
        size_t gi = (size_t)(row + rg) * HID + col;
        binput[gi] = f2bf(v);
        gm0[gi] = f2bf(fmaxf(v, 0.f));
      }
    }
  }
}

// ---------------- fused gather + GEMM ----------------
// OUT=0: gm_next = relu(binput + gathersum(msg) @ Wh)   [rows = NB]
// OUT=1: out[mol] = mean(relu([gather|fatoms] @ Wo + bo)) [rows = NA]
// Block: 64 rows x 512 cols, 512 threads (8 waves, wave w = col stripe w*64).
template <int OUT>
__global__ __launch_bounds__(512, 4) void fused_step(
    const u16* __restrict__ tree, const u16* __restrict__ gm_prev,
    const int* __restrict__ graph, const u16* __restrict__ Bt,
    const u16* __restrict__ binput, u16* __restrict__ gm_next,
    const float* __restrict__ fatoms, const float* __restrict__ bo,
    const int* __restrict__ scope, float* __restrict__ out) {
  const int K = OUT ? 576 : 512;
  const int NCH = K / 64;
  __shared__ __align__(16) u16 As[64 * 72];  // stride 72: bank-balanced
  const int t = threadIdx.x;
  const int lane = t & 63;
  const int w = t >> 6;  // col stripe
  const int l15 = lane & 15;
  const int q8 = (lane >> 4) * 8;
  const int mBase = blockIdx.x * 64;
  const int slot = t >> 3;  // 0..63: row within block
  const int sub = t & 7;    // 0..7: 8-element col group within chunk

  f32x4 acc[4][4];
#pragma unroll
  for (int i = 0; i < 4; i++)
#pragma unroll
    for (int j = 0; j < 4; j++)
#pragma unroll
      for (int rg = 0; rg < 4; rg++) acc[i][j][rg] = 0.f;

  const int* idx = graph + (size_t)(mBase + slot) * MAX_NB;
  // shared-offset trick: msg[idx] = (idx<8192 ? tree : gm_prev-8192*512)[idx*512]
  const u16* gm_sh = gm_prev - (size_t)NMESS * HID;

  for (int ch = 0; ch < NCH; ch++) {
    const int kb = ch * 64;
    __syncthreads();  // As free (prior chunk's MFMA reads done)
    float g[8] = {0.f, 0.f, 0.f, 0.f, 0.f, 0.f, 0.f, 0.f};
    if (OUT && ch == NCH - 1) {
      // fatoms chunk: A cols 512..575 = [fatoms(35) | zeros]
#pragma unroll
      for (int e = 0; e < 8; e++) {
        int c = sub * 8 + e;
        g[e] = (c < 35) ? fatoms[(size_t)(mBase + slot) * 35 + c] : 0.f;
      }
    } else {
#pragma unroll
      for (int j = 0; j < MAX_NB; j++) {
        int id = idx[j];
        const u16* base = (id < NMESS) ? tree : gm_sh;
        uint4 v = *(const uint4*)(base + (size_t)id * HID + kb + sub * 8);
        g[0] += bflo(v.x); g[1] += bfhi(v.x);
        g[2] += bflo(v.y); g[3] += bfhi(v.y);
        g[4] += bflo(v.z); g[5] += bfhi(v.z);
        g[6] += bflo(v.w); g[7] += bfhi(v.w);
      }
    }
    uint4 o;
    o.x = (u32)f2bf(g[0]) | ((u32)f2bf(g[1]) << 16);
    o.y = (u32)f2bf(g[2]) | ((u32)f2bf(g[3]) << 16);
    o.z = (u32)f2bf(g[4]) | ((u32)f2bf(g[5]) << 16);
    o.w = (u32)f2bf(g[6]) | ((u32)f2bf(g[7]) << 16);
    *(uint4*)(As + slot * 72 + sub * 8) = o;
    __syncthreads();
#pragma unroll
    for (int s = 0; s < 2; s++) {
      bf16x8 av[4], bv[4];
#pragma unroll
      for (int i = 0; i < 4; i++)
        av[i] = *(const bf16x8*)(As + (i * 16 + l15) * 72 + s * 32 + q8);
#pragma unroll
      for (int j = 0; j < 4; j++)
        bv[j] = *(const bf16x8*)(Bt + (size_t)(w * 64 + j * 16 + l15) * K + kb +
                                 s * 32 + q8);
#pragma unroll
      for (int i = 0; i < 4; i++)
#pragma unroll
        for (int j = 0; j < 4; j++)
          acc[i][j] = __builtin_amdgcn_mfma_f32_16x16x32_bf16(
              av[i], bv[j], acc[i][j], 0, 0, 0);
    }
  }

  if (OUT) {
#pragma unroll
    for (int m = 0; m < 2; m++) {
      int mol = (mBase >> 5) + m;
      float inv_le = 1.0f / (float)scope[mol * 2 + 1];
#pragma unroll
      for (int j = 0; j < 4; j++) {
        int col = w * 64 + j * 16 + l15;
        float bias = bo[col];
        float s = 0.f;
#pragma unroll
        for (int i = 2 * m; i < 2 * m + 2; i++)
#pragma unroll
          for (int rg = 0; rg < 4; rg++)
            s += fmaxf(acc[i][j][rg] + bias, 0.f);
        s += __shfl_xor(s, 16, 64);
        s += __shfl_xor(s, 32, 64);
        if (lane < 16) out[(size_t)mol * HID + col] = s * inv_le;
      }
    }
  } else {
#pragma unroll
    for (int i = 0; i < 4; i++) {
      int row = mBase + i * 16 + (lane >> 4) * 4;
#pragma unroll
      for (int j = 0; j < 4; j++) {
        int col = w * 64 + j * 16 + l15;
#pragma unroll
        for (int rg = 0; rg < 4; rg++) {
          size_t gi = (size_t)(row + rg) * HID + col;
          float v = acc[i][j][rg] + bf2f(binput[gi]);
          gm_next[gi] = f2bf(fmaxf(v, 0.f));
        }
      }
    }
  }
}

// ---------------- launch ----------------
extern "C" void kernel_launch(void* const* d_in, const int* in_sizes, int n_in,
                              void* d_out, int out_size, void* d_ws,
                              size_t ws_size, hipStream_t stream) {
  const float* fatoms = (const float*)d_in[0];
  const float* fbonds = (const float*)d_in[1];
  const int* agraph = (const int*)d_in[2];
  const int* bgraph = (const int*)d_in[3];
  const int* scope = (const int*)d_in[4];
  const float* tree = (const float*)d_in[5];
  const float* Wi = (const float*)d_in[6];
  const float* Wh = (const float*)d_in[7];
  const float* Wo = (const float*)d_in[8];
  const float* bo = (const float*)d_in[9];
  float* out = (float*)d_out;

  char* ws = (char*)d_ws;
  // tree_bf 8.39MB | gmA 67.1MB | gmB 67.1MB | binput 67.1MB | weights 1.2MB
  u16* tree_bf = (u16*)(ws);
  u16* gmA = (u16*)(ws + 8388608ull);
  u16* gmB = (u16*)(ws + 75497472ull);
  u16* binput = (u16*)(ws + 142606336ull);
  u16* wi_t = (u16*)(ws + 209715200ull);
  u16* wh_t = (u16*)(ws + 209780736ull);
  u16* wo_t = (u16*)(ws + 210305024ull);
  u16* fbpad = gmB;  // alias: fbpad dead before gmB is first written

  prep_kernel<<<35072, 256, 0, stream>>>(fbonds, tree, Wi, Wh, Wo, tree_bf,
                                         fbpad, wi_t, wh_t, wo_t);

  init_gemm<<<dim3(NB / 128, 4), 256, 0, stream>>>(fbpad, wi_t, binput, gmA);

  // 5 message-passing steps, ping-pong gmA<->gmB (final lands in gmB)
  u16* prev = gmA;
  u16* next = gmB;
  for (int d = 0; d < 5; d++) {
    fused_step<0><<<NB / 64, 512, 0, stream>>>(tree_bf, prev, bgraph, wh_t,
                                               binput, next, nullptr, nullptr,
                                               nullptr, nullptr);
    u16* tmp = prev; prev = next; next = tmp;
  }

  fused_step<1><<<NA / 64, 512, 0, stream>>>(tree_bf, prev, agraph, wo_t,
                                             nullptr, nullptr, fatoms, bo,
                                             scope, out);
}

// Round 3
// 1295.488 us; speedup vs baseline: 1.0304x; 1.0304x over previous
//
#include <hip/hip_runtime.h>
#include <stdint.h>

// JTMPN on MI355X — round 3: revert to split kernels (r1 structure, 1292us),
// restructure gathers for deep memory ILP: all 15 indexed 1KB row-loads
// issued before any accumulation (r1 had ~2-3 in flight @ VGPR_Count=44,
// latency-limited at ~12 cy/line).

#define MAX_NB 15
#define HID 512
#define NA 32768
#define NB 65536
#define NMESS 8192

typedef unsigned short u16;
typedef unsigned int u32;
typedef __bf16 bf16x8 __attribute__((ext_vector_type(8)));
typedef float f32x4 __attribute__((ext_vector_type(4)));

__device__ __forceinline__ u16 f2bf(float f) {
  u32 u = __builtin_bit_cast(u32, f);
  u32 r = (u + 0x7fffu + ((u >> 16) & 1u)) >> 16;
  return (u16)r;
}
__device__ __forceinline__ float bf2f(u16 b) {
  u32 u = ((u32)b) << 16;
  return __builtin_bit_cast(float, u);
}
__device__ __forceinline__ float bflo(u32 u) {
  return __builtin_bit_cast(float, u << 16);
}
__device__ __forceinline__ float bfhi(u32 u) {
  return __builtin_bit_cast(float, u & 0xffff0000u);
}

__device__ __forceinline__ void async16(const u16* g, u16* l) {
  __builtin_amdgcn_global_load_lds(
      (const __attribute__((address_space(1))) u32*)g,
      (__attribute__((address_space(3))) u32*)l, 16, 0, 0);
}

// ---------------- prep: fp32 -> bf16 conversions / transposes ----------------
__global__ __launch_bounds__(256) void prep_kernel(
    const float* __restrict__ fbonds, const float* __restrict__ tree,
    const float* __restrict__ Wi, const float* __restrict__ Wh,
    const float* __restrict__ Wo, u16* __restrict__ msg,
    u16* __restrict__ fbpad, u16* __restrict__ wi_t, u16* __restrict__ wh_t,
    u16* __restrict__ wo_t) {
  int t = blockIdx.x * 256 + threadIdx.x;
  const int N0 = NMESS * HID;  // 4194304
  const int N1 = NB * 64;      // 4194304
  const int N2 = 512 * 64;
  const int N3 = 512 * 512;
  const int N4 = 512 * 576;
  if (t < N0) { msg[t] = f2bf(tree[t]); return; }
  t -= N0;
  if (t < N1) {
    int row = t >> 6, c = t & 63;
    fbpad[t] = (c < 40) ? f2bf(fbonds[row * 40 + c]) : (u16)0;
    return;
  }
  t -= N1;
  if (t < N2) {
    int n = t >> 6, k = t & 63;
    wi_t[t] = (k < 40) ? f2bf(Wi[k * 512 + n]) : (u16)0;
    return;
  }
  t -= N2;
  if (t < N3) {
    int n = t >> 9, k = t & 511;
    wh_t[t] = f2bf(Wh[k * 512 + n]);
    return;
  }
  t -= N3;
  if (t < N4) {
    int n = t / 576, k = t - n * 576;
    float v = 0.f;
    if (k < 512) v = Wo[(35 + k) * 512 + n];        // nei part
    else if (k < 547) v = Wo[(k - 512) * 512 + n];  // fatoms part
    wo_t[t] = f2bf(v);
    return;
  }
}

// ---------------- gather-sum: wave per row, all 15 loads in flight ----------
__global__ __launch_bounds__(256) void gather_bonds(
    const u16* __restrict__ msg, const int* __restrict__ bgraph,
    u16* __restrict__ nei) {
  int row = blockIdx.x * 4 + (threadIdx.x >> 6);
  int lane = threadIdx.x & 63;
  const int* idxp = bgraph + row * MAX_NB;
  int ids[MAX_NB];
#pragma unroll
  for (int j = 0; j < MAX_NB; j++) ids[j] = idxp[j];  // wave-uniform -> s_load
  const u16* base = msg + lane * 8;
  uint4 v[MAX_NB];
#pragma unroll
  for (int j = 0; j < MAX_NB; j++)
    v[j] = *(const uint4*)(base + (size_t)ids[j] * HID);
  float acc[8] = {0, 0, 0, 0, 0, 0, 0, 0};
#pragma unroll
  for (int j = 0; j < MAX_NB; j++) {
    acc[0] += bflo(v[j].x); acc[1] += bfhi(v[j].x);
    acc[2] += bflo(v[j].y); acc[3] += bfhi(v[j].y);
    acc[4] += bflo(v[j].z); acc[5] += bfhi(v[j].z);
    acc[6] += bflo(v[j].w); acc[7] += bfhi(v[j].w);
  }
  uint4 o;
  o.x = (u32)f2bf(acc[0]) | ((u32)f2bf(acc[1]) << 16);
  o.y = (u32)f2bf(acc[2]) | ((u32)f2bf(acc[3]) << 16);
  o.z = (u32)f2bf(acc[4]) | ((u32)f2bf(acc[5]) << 16);
  o.w = (u32)f2bf(acc[6]) | ((u32)f2bf(acc[7]) << 16);
  *(uint4*)(nei + (size_t)row * HID + lane * 8) = o;
}

// atom gather also builds ainput row: [nei(512) | fatoms(35) | zeros(29)]
__global__ __launch_bounds__(256) void gather_atoms(
    const u16* __restrict__ msg, const int* __restrict__ agraph,
    const float* __restrict__ fatoms, u16* __restrict__ ainput) {
  int row = blockIdx.x * 4 + (threadIdx.x >> 6);
  int lane = threadIdx.x & 63;
  const int* idxp = agraph + row * MAX_NB;
  int ids[MAX_NB];
#pragma unroll
  for (int j = 0; j < MAX_NB; j++) ids[j] = idxp[j];
  const u16* base = msg + lane * 8;
  uint4 v[MAX_NB];
#pragma unroll
  for (int j = 0; j < MAX_NB; j++)
    v[j] = *(const uint4*)(base + (size_t)ids[j] * HID);
  float acc[8] = {0, 0, 0, 0, 0, 0, 0, 0};
#pragma unroll
  for (int j = 0; j < MAX_NB; j++) {
    acc[0] += bflo(v[j].x); acc[1] += bfhi(v[j].x);
    acc[2] += bflo(v[j].y); acc[3] += bfhi(v[j].y);
    acc[4] += bflo(v[j].z); acc[5] += bfhi(v[j].z);
    acc[6] += bflo(v[j].w); acc[7] += bfhi(v[j].w);
  }
  uint4 o;
  o.x = (u32)f2bf(acc[0]) | ((u32)f2bf(acc[1]) << 16);
  o.y = (u32)f2bf(acc[2]) | ((u32)f2bf(acc[3]) << 16);
  o.z = (u32)f2bf(acc[4]) | ((u32)f2bf(acc[5]) << 16);
  o.w = (u32)f2bf(acc[6]) | ((u32)f2bf(acc[7]) << 16);
  u16* arow = ainput + (size_t)row * 576;
  *(uint4*)(arow + lane * 8) = o;
  float tv = (lane < 35) ? fatoms[(size_t)row * 35 + lane] : 0.f;
  arow[512 + lane] = f2bf(tv);
}

// ---------------- 128x128 bf16 MFMA GEMM, templated epilogue ----------------
// EPI 0: binput=acc, msg=relu(acc);  EPI 1: msg=relu(acc+binput);
// EPI 2: out[mol] = mean(relu(acc+bias))
template <int EPI>
__global__ __launch_bounds__(256) void gemm_k(
    const u16* __restrict__ A, const u16* __restrict__ Bt, int K,
    u16* __restrict__ binput, u16* __restrict__ msgout,
    const float* __restrict__ bo, const int* __restrict__ scope,
    float* __restrict__ out) {
  __shared__ __align__(16) u16 As[128 * 32];
  __shared__ __align__(16) u16 Bs[128 * 32];
  const int t = threadIdx.x;
  const int lane = t & 63;
  const int w = t >> 6;
  const int wm = w & 1, wn = w >> 1;
  const int mBase = blockIdx.x * 128;
  const int nBase = blockIdx.y * 128;
  const int r = t >> 2;
  const int c8 = (t & 3) * 8;
  const int q8 = (lane >> 4) * 8;
  const int l15 = lane & 15;

  f32x4 acc[4][4];
#pragma unroll
  for (int i = 0; i < 4; i++)
#pragma unroll
    for (int j = 0; j < 4; j++)
#pragma unroll
      for (int rg = 0; rg < 4; rg++) acc[i][j][rg] = 0.f;

  for (int kb = 0; kb < K; kb += 32) {
    __syncthreads();
    async16(A + (size_t)(mBase + r) * K + kb + c8, As + r * 32 + c8);
    async16(A + (size_t)(mBase + r + 64) * K + kb + c8, As + (r + 64) * 32 + c8);
    async16(Bt + (size_t)(nBase + r) * K + kb + c8, Bs + r * 32 + c8);
    async16(Bt + (size_t)(nBase + r + 64) * K + kb + c8, Bs + (r + 64) * 32 + c8);
    __syncthreads();
    bf16x8 av[4], bv[4];
#pragma unroll
    for (int i = 0; i < 4; i++)
      av[i] = *(const bf16x8*)(As + (wm * 64 + i * 16 + l15) * 32 + q8);
#pragma unroll
    for (int j = 0; j < 4; j++)
      bv[j] = *(const bf16x8*)(Bs + (wn * 64 + j * 16 + l15) * 32 + q8);
#pragma unroll
    for (int i = 0; i < 4; i++)
#pragma unroll
      for (int j = 0; j < 4; j++)
        acc[i][j] = __builtin_amdgcn_mfma_f32_16x16x32_bf16(av[i], bv[j],
                                                            acc[i][j], 0, 0, 0);
  }

  if (EPI == 2) {
#pragma unroll
    for (int m = 0; m < 2; m++) {
      int mol = (mBase + wm * 64 + m * 32) >> 5;
      float inv_le = 1.0f / (float)scope[mol * 2 + 1];
#pragma unroll
      for (int j = 0; j < 4; j++) {
        int col = nBase + wn * 64 + j * 16 + l15;
        float bias = bo[col];
        float s = 0.f;
#pragma unroll
        for (int i = 2 * m; i < 2 * m + 2; i++)
#pragma unroll
          for (int rg = 0; rg < 4; rg++)
            s += fmaxf(acc[i][j][rg] + bias, 0.f);
        s += __shfl_xor(s, 16, 64);
        s += __shfl_xor(s, 32, 64);
        if (lane < 16) out[(size_t)mol * HID + col] = s * inv_le;
      }
    }
  } else {
#pragma unroll
    for (int i = 0; i < 4; i++) {
      int row = mBase + wm * 64 + i * 16 + (lane >> 4) * 4;
#pragma unroll
      for (int j = 0; j < 4; j++) {
        int col = nBase + wn * 64 + j * 16 + l15;
#pragma unroll
        for (int rg = 0; rg < 4; rg++) {
          float v = acc[i][j][rg];
          size_t gi = (size_t)(row + rg) * HID + col;
          if (EPI == 0) {
            binput[gi] = f2bf(v);
            msgout[gi + (size_t)NMESS * HID] = f2bf(fmaxf(v, 0.f));
          } else {
            v += bf2f(binput[gi]);
            msgout[gi + (size_t)NMESS * HID] = f2bf(fmaxf(v, 0.f));
          }
        }
      }
    }
  }
}

// ---------------- launch ----------------
extern "C" void kernel_launch(void* const* d_in, const int* in_sizes, int n_in,
                              void* d_out, int out_size, void* d_ws,
                              size_t ws_size, hipStream_t stream) {
  const float* fatoms = (const float*)d_in[0];
  const float* fbonds = (const float*)d_in[1];
  const int* agraph = (const int*)d_in[2];
  const int* bgraph = (const int*)d_in[3];
  const int* scope = (const int*)d_in[4];
  const float* tree = (const float*)d_in[5];
  const float* Wi = (const float*)d_in[6];
  const float* Wh = (const float*)d_in[7];
  const float* Wo = (const float*)d_in[8];
  const float* bo = (const float*)d_in[9];
  float* out = (float*)d_out;

  char* ws = (char*)d_ws;
  // layout (bytes): msg 75,497,472 | binput 67,108,864 | nei 67,108,864 |
  //                 wi_t | wh_t | wo_t  (~211 MB)
  u16* msg = (u16*)(ws);
  u16* binput = (u16*)(ws + 75497472ull);
  u16* nei = (u16*)(ws + 142606336ull);
  u16* wi_t = (u16*)(ws + 209715200ull);
  u16* wh_t = (u16*)(ws + 209780736ull);
  u16* wo_t = (u16*)(ws + 210305024ull);
  u16* fbpad = nei;     // alias: fbpad dead before first gather writes nei
  u16* ainput = binput; // alias: binput dead after last EPI=1 gemm

  prep_kernel<<<35072, 256, 0, stream>>>(fbonds, tree, Wi, Wh, Wo, msg, fbpad,
                                         wi_t, wh_t, wo_t);

  dim3 gB(NB / 128, 4);
  gemm_k<0><<<gB, 256, 0, stream>>>(fbpad, wi_t, 64, binput, msg, nullptr,
                                    nullptr, nullptr);
  for (int d = 0; d < 5; d++) {
    gather_bonds<<<NB / 4, 256, 0, stream>>>(msg, bgraph, nei);
    gemm_k<1><<<gB, 256, 0, stream>>>(nei, wh_t, 512, binput, msg, nullptr,
                                      nullptr, nullptr);
  }
  gather_atoms<<<NA / 4, 256, 0, stream>>>(msg, agraph, fatoms, ainput);
  dim3 gO(NA / 128, 4);
  gemm_k<2><<<gO, 256, 0, stream>>>(ainput, wo_t, 576, nullptr, nullptr, bo,
                                    scope, out);
}

// Round 4
// 1273.822 us; speedup vs baseline: 1.0479x; 1.0170x over previous
//
#include <hip/hip_runtime.h>
#include <stdint.h>

// JTMPN on MI355X — round 4:
//  (a) gather via global_load_lds DMA (no VGPR dest -> deep miss queue;
//      r3 showed compiler collapses VGPR-path ILP, 3.65 TB/s MSHR-limited)
//  (b) GEMM blockIdx%8 XCD swizzle, n-siblings co-resident -> A-tile L2 reuse

#define MAX_NB 15
#define HID 512
#define NA 32768
#define NB 65536
#define NMESS 8192

typedef unsigned short u16;
typedef unsigned int u32;
typedef __bf16 bf16x8 __attribute__((ext_vector_type(8)));
typedef float f32x4 __attribute__((ext_vector_type(4)));

__device__ __forceinline__ u16 f2bf(float f) {
  u32 u = __builtin_bit_cast(u32, f);
  u32 r = (u + 0x7fffu + ((u >> 16) & 1u)) >> 16;
  return (u16)r;
}
__device__ __forceinline__ float bf2f(u16 b) {
  u32 u = ((u32)b) << 16;
  return __builtin_bit_cast(float, u);
}
__device__ __forceinline__ float bflo(u32 u) {
  return __builtin_bit_cast(float, u << 16);
}
__device__ __forceinline__ float bfhi(u32 u) {
  return __builtin_bit_cast(float, u & 0xffff0000u);
}

__device__ __forceinline__ void async16(const u16* g, u16* l) {
  __builtin_amdgcn_global_load_lds(
      (const __attribute__((address_space(1))) u32*)g,
      (__attribute__((address_space(3))) u32*)l, 16, 0, 0);
}

// ---------------- prep: fp32 -> bf16 conversions / transposes ----------------
__global__ __launch_bounds__(256) void prep_kernel(
    const float* __restrict__ fbonds, const float* __restrict__ tree,
    const float* __restrict__ Wi, const float* __restrict__ Wh,
    const float* __restrict__ Wo, u16* __restrict__ msg,
    u16* __restrict__ fbpad, u16* __restrict__ wi_t, u16* __restrict__ wh_t,
    u16* __restrict__ wo_t) {
  int t = blockIdx.x * 256 + threadIdx.x;
  const int N0 = NMESS * HID;  // 4194304
  const int N1 = NB * 64;      // 4194304
  const int N2 = 512 * 64;
  const int N3 = 512 * 512;
  const int N4 = 512 * 576;
  if (t < N0) { msg[t] = f2bf(tree[t]); return; }
  t -= N0;
  if (t < N1) {
    int row = t >> 6, c = t & 63;
    fbpad[t] = (c < 40) ? f2bf(fbonds[row * 40 + c]) : (u16)0;
    return;
  }
  t -= N1;
  if (t < N2) {
    int n = t >> 6, k = t & 63;
    wi_t[t] = (k < 40) ? f2bf(Wi[k * 512 + n]) : (u16)0;
    return;
  }
  t -= N2;
  if (t < N3) {
    int n = t >> 9, k = t & 511;
    wh_t[t] = f2bf(Wh[k * 512 + n]);
    return;
  }
  t -= N3;
  if (t < N4) {
    int n = t / 576, k = t - n * 576;
    float v = 0.f;
    if (k < 512) v = Wo[(35 + k) * 512 + n];        // nei part
    else if (k < 547) v = Wo[(k - 512) * 512 + n];  // fatoms part
    wo_t[t] = f2bf(v);
    return;
  }
}

// ---------------- gather via LDS-DMA ----------------
// Wave per row-group: each wave handles 4 rows; per row, 15 indexed 1KB rows
// DMA'd to LDS in batches of 8+7 (one async16 instruction = one full row:
// 64 lanes x 16B). 8KB LDS/wave -> 32KB/block -> ~5 blocks/CU.
template <int ATOMS>
__global__ __launch_bounds__(256) void gather_dma(
    const u16* __restrict__ msg, const int* __restrict__ graph,
    const float* __restrict__ fatoms, u16* __restrict__ outbuf) {
  __shared__ __align__(16) u16 sbuf[4][8][HID];  // 32 KB
  const int lane = threadIdx.x & 63;
  const int w = threadIdx.x >> 6;
  u16* buf = &sbuf[w][0][0];
  const int rowBase = (blockIdx.x * 4 + w) * 4;
  const int OSTRIDE = ATOMS ? 576 : HID;

  for (int r = 0; r < 4; r++) {
    const int row = rowBase + r;
    const int* idxp = graph + row * MAX_NB;
    int myid = (lane < MAX_NB) ? idxp[lane] : 0;
    int ids[MAX_NB];
#pragma unroll
    for (int j = 0; j < MAX_NB; j++) ids[j] = __shfl(myid, j, 64);

    float acc[8] = {0, 0, 0, 0, 0, 0, 0, 0};
    // batch 1: rows 0..7
    __builtin_amdgcn_s_waitcnt(0);  // prior LDS reads done before DMA overwrite
#pragma unroll
    for (int j = 0; j < 8; j++)
      async16(msg + (size_t)ids[j] * HID + lane * 8, buf + j * HID + lane * 8);
    __builtin_amdgcn_s_waitcnt(0);  // DMA landed
#pragma unroll
    for (int j = 0; j < 8; j++) {
      uint4 v = *(const uint4*)(buf + j * HID + lane * 8);
      acc[0] += bflo(v.x); acc[1] += bfhi(v.x);
      acc[2] += bflo(v.y); acc[3] += bfhi(v.y);
      acc[4] += bflo(v.z); acc[5] += bfhi(v.z);
      acc[6] += bflo(v.w); acc[7] += bfhi(v.w);
    }
    // batch 2: rows 8..14
    __builtin_amdgcn_s_waitcnt(0);
#pragma unroll
    for (int j = 8; j < MAX_NB; j++)
      async16(msg + (size_t)ids[j] * HID + lane * 8,
              buf + (j - 8) * HID + lane * 8);
    __builtin_amdgcn_s_waitcnt(0);
#pragma unroll
    for (int j = 8; j < MAX_NB; j++) {
      uint4 v = *(const uint4*)(buf + (j - 8) * HID + lane * 8);
      acc[0] += bflo(v.x); acc[1] += bfhi(v.x);
      acc[2] += bflo(v.y); acc[3] += bfhi(v.y);
      acc[4] += bflo(v.z); acc[5] += bfhi(v.z);
      acc[6] += bflo(v.w); acc[7] += bfhi(v.w);
    }
    uint4 o;
    o.x = (u32)f2bf(acc[0]) | ((u32)f2bf(acc[1]) << 16);
    o.y = (u32)f2bf(acc[2]) | ((u32)f2bf(acc[3]) << 16);
    o.z = (u32)f2bf(acc[4]) | ((u32)f2bf(acc[5]) << 16);
    o.w = (u32)f2bf(acc[6]) | ((u32)f2bf(acc[7]) << 16);
    u16* orow = outbuf + (size_t)row * OSTRIDE;
    *(uint4*)(orow + lane * 8) = o;
    if (ATOMS) {
      float tv = (lane < 35) ? fatoms[(size_t)row * 35 + lane] : 0.f;
      orow[512 + lane] = f2bf(tv);
    }
  }
}

// ---------------- 128x128 bf16 MFMA GEMM, XCD-swizzled 1D grid ---------------
// grid = mtiles*4 blocks; xcd=L&7 owns mtiles [xcd*mtx, (xcd+1)*mtx),
// n-tile inner so 4 n-siblings of an m-tile are co-resident on one XCD.
// EPI 0: binput=acc, msg=relu(acc);  EPI 1: msg=relu(acc+binput);
// EPI 2: out[mol] = mean(relu(acc+bias))
template <int EPI>
__global__ __launch_bounds__(256) void gemm_k(
    const u16* __restrict__ A, const u16* __restrict__ Bt, int K, int mtx,
    u16* __restrict__ binput, u16* __restrict__ msgout,
    const float* __restrict__ bo, const int* __restrict__ scope,
    float* __restrict__ out) {
  __shared__ __align__(16) u16 As[128 * 32];
  __shared__ __align__(16) u16 Bs[128 * 32];
  const int L = blockIdx.x;
  const int xcd = L & 7;
  const int q = L >> 3;
  const int mBase = (xcd * mtx + (q >> 2)) * 128;
  const int nBase = (q & 3) * 128;
  const int t = threadIdx.x;
  const int lane = t & 63;
  const int w = t >> 6;
  const int wm = w & 1, wn = w >> 1;
  const int r = t >> 2;
  const int c8 = (t & 3) * 8;
  const int q8 = (lane >> 4) * 8;
  const int l15 = lane & 15;

  f32x4 acc[4][4];
#pragma unroll
  for (int i = 0; i < 4; i++)
#pragma unroll
    for (int j = 0; j < 4; j++)
#pragma unroll
      for (int rg = 0; rg < 4; rg++) acc[i][j][rg] = 0.f;

  for (int kb = 0; kb < K; kb += 32) {
    __syncthreads();
    async16(A + (size_t)(mBase + r) * K + kb + c8, As + r * 32 + c8);
    async16(A + (size_t)(mBase + r + 64) * K + kb + c8, As + (r + 64) * 32 + c8);
    async16(Bt + (size_t)(nBase + r) * K + kb + c8, Bs + r * 32 + c8);
    async16(Bt + (size_t)(nBase + r + 64) * K + kb + c8, Bs + (r + 64) * 32 + c8);
    __syncthreads();
    bf16x8 av[4], bv[4];
#pragma unroll
    for (int i = 0; i < 4; i++)
      av[i] = *(const bf16x8*)(As + (wm * 64 + i * 16 + l15) * 32 + q8);
#pragma unroll
    for (int j = 0; j < 4; j++)
      bv[j] = *(const bf16x8*)(Bs + (wn * 64 + j * 16 + l15) * 32 + q8);
#pragma unroll
    for (int i = 0; i < 4; i++)
#pragma unroll
      for (int j = 0; j < 4; j++)
        acc[i][j] = __builtin_amdgcn_mfma_f32_16x16x32_bf16(av[i], bv[j],
                                                            acc[i][j], 0, 0, 0);
  }

  if (EPI == 2) {
#pragma unroll
    for (int m = 0; m < 2; m++) {
      int mol = (mBase + wm * 64 + m * 32) >> 5;
      float inv_le = 1.0f / (float)scope[mol * 2 + 1];
#pragma unroll
      for (int j = 0; j < 4; j++) {
        int col = nBase + wn * 64 + j * 16 + l15;
        float bias = bo[col];
        float s = 0.f;
#pragma unroll
        for (int i = 2 * m; i < 2 * m + 2; i++)
#pragma unroll
          for (int rg = 0; rg < 4; rg++)
            s += fmaxf(acc[i][j][rg] + bias, 0.f);
        s += __shfl_xor(s, 16, 64);
        s += __shfl_xor(s, 32, 64);
        if (lane < 16) out[(size_t)mol * HID + col] = s * inv_le;
      }
    }
  } else {
#pragma unroll
    for (int i = 0; i < 4; i++) {
      int row = mBase + wm * 64 + i * 16 + (lane >> 4) * 4;
#pragma unroll
      for (int j = 0; j < 4; j++) {
        int col = nBase + wn * 64 + j * 16 + l15;
#pragma unroll
        for (int rg = 0; rg < 4; rg++) {
          float v = acc[i][j][rg];
          size_t gi = (size_t)(row + rg) * HID + col;
          if (EPI == 0) {
            binput[gi] = f2bf(v);
            msgout[gi + (size_t)NMESS * HID] = f2bf(fmaxf(v, 0.f));
          } else {
            v += bf2f(binput[gi]);
            msgout[gi + (size_t)NMESS * HID] = f2bf(fmaxf(v, 0.f));
          }
        }
      }
    }
  }
}

// ---------------- launch ----------------
extern "C" void kernel_launch(void* const* d_in, const int* in_sizes, int n_in,
                              void* d_out, int out_size, void* d_ws,
                              size_t ws_size, hipStream_t stream) {
  const float* fatoms = (const float*)d_in[0];
  const float* fbonds = (const float*)d_in[1];
  const int* agraph = (const int*)d_in[2];
  const int* bgraph = (const int*)d_in[3];
  const int* scope = (const int*)d_in[4];
  const float* tree = (const float*)d_in[5];
  const float* Wi = (const float*)d_in[6];
  const float* Wh = (const float*)d_in[7];
  const float* Wo = (const float*)d_in[8];
  const float* bo = (const float*)d_in[9];
  float* out = (float*)d_out;

  char* ws = (char*)d_ws;
  u16* msg = (u16*)(ws);
  u16* binput = (u16*)(ws + 75497472ull);
  u16* nei = (u16*)(ws + 142606336ull);
  u16* wi_t = (u16*)(ws + 209715200ull);
  u16* wh_t = (u16*)(ws + 209780736ull);
  u16* wo_t = (u16*)(ws + 210305024ull);
  u16* fbpad = nei;     // alias: fbpad dead before first gather writes nei
  u16* ainput = binput; // alias: binput dead after last EPI=1 gemm

  prep_kernel<<<35072, 256, 0, stream>>>(fbonds, tree, Wi, Wh, Wo, msg, fbpad,
                                         wi_t, wh_t, wo_t);

  // init: M=65536 -> 512 mtiles, 64 per XCD
  gemm_k<0><<<2048, 256, 0, stream>>>(fbpad, wi_t, 64, 64, binput, msg,
                                      nullptr, nullptr, nullptr);
  for (int d = 0; d < 5; d++) {
    gather_dma<0><<<NB / 16, 256, 0, stream>>>(msg, bgraph, nullptr, nei);
    gemm_k<1><<<2048, 256, 0, stream>>>(nei, wh_t, 512, 64, binput, msg,
                                        nullptr, nullptr, nullptr);
  }
  gather_dma<1><<<NA / 16, 256, 0, stream>>>(msg, agraph, fatoms, ainput);
  // out: M=32768 -> 256 mtiles, 32 per XCD
  gemm_k<2><<<1024, 256, 0, stream>>>(ainput, wo_t, 576, 32, nullptr, nullptr,
                                      bo, scope, out);
}